// Round 10
// baseline (610.541 us; speedup 1.0000x reference)
//
#include <hip/hip_runtime.h>

#define L 1024
#define DIM 1024
#define NB 16

typedef unsigned short u16;
typedef __attribute__((ext_vector_type(4))) float f32x4;
typedef __attribute__((ext_vector_type(8))) short s16x8;

__device__ __forceinline__ float bf2f(u16 x){
  union { unsigned u; float f; } c; c.u = ((unsigned)x) << 16; return c.f;
}
__device__ __forceinline__ u16 f2bf(float f){
  union { float f; unsigned u; } c; c.f = f;
  unsigned r = c.u + 0x7fffu + ((c.u >> 16) & 1u);
  return (u16)(r >> 16);
}
__device__ __forceinline__ void gload_lds16(const void* g, void* l){
  __builtin_amdgcn_global_load_lds(
      (const __attribute__((address_space(1))) void*)g,
      (__attribute__((address_space(3))) void*)l, 16, 0, 0);
}

// ---------------- weights fp32 -> bf16 (once) ----------------
struct WPtrs { const float* p[6]; };

__global__ __launch_bounds__(256) void k_wconv(WPtrs wp, u16* out){
  long idx = (long)blockIdx.x * blockDim.x + threadIdx.x;
  long base = idx * 4;
  int w = (int)(base >> 20);
  long off = base & ((1 << 20) - 1);
  float4 v = *(const float4*)(wp.p[w] + off);
  ushort4 o;
  o.x = f2bf(v.x); o.y = f2bf(v.y); o.z = f2bf(v.z); o.w = f2bf(v.w);
  *(ushort4*)(out + base) = o;
}

// ---------------- V [D,L] f32 -> Vt [L,D] bf16 (vectorized) ----------------
__global__ __launch_bounds__(256) void k_transpose(const float* X, u16* Xt, int bo){
  __shared__ u16 tile[64][68];
  int b = blockIdx.y;
  int d0 = (blockIdx.x >> 4) * 64;
  int l0 = (blockIdx.x & 15) * 64;
  const float* Xb = X + (long)(bo + b) * DIM * L;
  u16* Xtb = Xt + (long)b * L * DIM;
  int q = threadIdx.x & 15, g = threadIdx.x >> 4;
  for (int r = g; r < 64; r += 16){
    float4 v = *(const float4*)(Xb + (long)(d0 + r) * L + l0 + q * 4);
    ushort4 h; h.x = f2bf(v.x); h.y = f2bf(v.y); h.z = f2bf(v.z); h.w = f2bf(v.w);
    *(ushort4*)&tile[r][q * 4] = h;
  }
  __syncthreads();
  for (int r = g; r < 64; r += 16){
    ushort4 h;
    h.x = tile[q * 4 + 0][r]; h.y = tile[q * 4 + 1][r];
    h.z = tile[q * 4 + 2][r]; h.w = tile[q * 4 + 3][r];
    *(ushort4*)&Xtb[(long)(l0 + r) * DIM + d0 + q * 4] = h;
  }
}

// ------- T: column inv-norm rT + normalized transpose Tnt; also zeros Z1,Z2 -------
__global__ __launch_bounds__(256) void k_tnorm(const float* T_, u16* Tnt, float* rT,
                                               float* Z1, float* Z2, int bo){
  __shared__ float red[16][16][5];
  __shared__ float rn[64];
  __shared__ u16 tile[64][68];
  int b = blockIdx.y; int l0 = blockIdx.x * 64;
  const float* Tb = T_ + (long)(bo + b) * DIM * L;
  int q = threadIdx.x & 15, g = threadIdx.x >> 4;
  if (threadIdx.x < 64){
    Z1[(long)b * L + l0 + threadIdx.x] = 0.f;
    Z2[(long)b * L + l0 + threadIdx.x] = 0.f;
  }
  f32x4 ss = {0.f, 0.f, 0.f, 0.f};
  for (int d = g; d < DIM; d += 16){
    float4 v = *(const float4*)(Tb + (long)d * L + l0 + q * 4);
    f32x4 vv = {v.x, v.y, v.z, v.w};
    ss += vv * vv;
  }
  #pragma unroll
  for (int e = 0; e < 4; e++) red[g][q][e] = ss[e];
  __syncthreads();
  if (threadIdx.x < 64){
    int c = threadIdx.x;
    float n = 0.f;
    #pragma unroll
    for (int gg = 0; gg < 16; gg++) n += red[gg][c >> 2][c & 3];
    float r = 1.0f / fmaxf(sqrtf(n), 1e-12f);
    rn[c] = r;
    rT[(long)b * L + l0 + c] = r;
  }
  __syncthreads();
  float r0 = rn[q * 4], r1 = rn[q * 4 + 1], r2 = rn[q * 4 + 2], r3 = rn[q * 4 + 3];
  u16* Tntb = Tnt + (long)b * L * DIM;
  for (int ch = 0; ch < 16; ch++){
    int dbase = ch * 64;
    for (int r = g; r < 64; r += 16){
      float4 v = *(const float4*)(Tb + (long)(dbase + r) * L + l0 + q * 4);
      ushort4 h;
      h.x = f2bf(v.x * r0); h.y = f2bf(v.y * r1);
      h.z = f2bf(v.z * r2); h.w = f2bf(v.w * r3);
      *(ushort4*)&tile[r][q * 4] = h;
    }
    __syncthreads();
    for (int r = g; r < 64; r += 16){
      ushort4 h;
      h.x = tile[q * 4 + 0][r]; h.y = tile[q * 4 + 1][r];
      h.z = tile[q * 4 + 2][r]; h.w = tile[q * 4 + 3][r];
      *(ushort4*)&Tntb[(long)(l0 + r) * DIM + dbase + q * 4] = h;
    }
    __syncthreads();
  }
}

// ================= merged 256x256 8-phase bt-GEMM =================
// Up to 4 independent sub-GEMMs per dispatch. Counted vmcnt ledger as r9;
// compiler-scheduled lgkm waits (no hard lgkmcnt(0)/sched_barrier pin) so
// fragment-read tails overlap MFMA heads within each phase.
// epi: 0 relu | 1 exp(acc*scale) + column-sum atomics to Z | 2 relu * (1/Z[col]) | 3 plain

struct GemmDesc {
  const u16* A[4]; const u16* B[4]; u16* C[4];
  float* Z[4];
  long sA[4], sB[4], sC[4];
  int epi[4];
  float scale;
};

#define VM6 asm volatile("s_waitcnt vmcnt(6)" ::: "memory")
#define VM8 asm volatile("s_waitcnt vmcnt(8)" ::: "memory")
#define VM4 asm volatile("s_waitcnt vmcnt(4)" ::: "memory")
#define VM0 asm volatile("s_waitcnt vmcnt(0)" ::: "memory")

#define PH(slot, mq, nq, LA, LB, STAGE, WAITC) do {                           \
  if (LA){                                                                    \
    _Pragma("unroll")                                                         \
    for (int f = 0; f < 4; f++){                                              \
      av[f][0] = *(const s16x8*)&lds[(slot)*16384 + arow + (mq)*4096 + f*1024 + cko0]; \
      av[f][1] = *(const s16x8*)&lds[(slot)*16384 + arow + (mq)*4096 + f*1024 + cko1]; \
    }                                                                         \
  }                                                                           \
  if (LB){                                                                    \
    _Pragma("unroll")                                                         \
    for (int g2 = 0; g2 < 2; g2++){                                           \
      bv[nq][g2][0] = *(const s16x8*)&lds[32768 + (slot)*16384 + brow + (nq)*2048 + g2*1024 + cko0]; \
      bv[nq][g2][1] = *(const s16x8*)&lds[32768 + (slot)*16384 + brow + (nq)*2048 + g2*1024 + cko1]; \
    }                                                                         \
  }                                                                           \
  STAGE;                                                                      \
  WAITC;                                                                      \
  __builtin_amdgcn_s_barrier();                                               \
  __builtin_amdgcn_s_setprio(1);                                              \
  _Pragma("unroll")                                                           \
  for (int f = 0; f < 4; f++)                                                 \
    _Pragma("unroll")                                                         \
    for (int g2 = 0; g2 < 2; g2++){                                           \
      acc[(mq)*4+f][(nq)*2+g2] = __builtin_amdgcn_mfma_f32_16x16x32_bf16(     \
          av[f][0], bv[nq][g2][0], acc[(mq)*4+f][(nq)*2+g2], 0, 0, 0);        \
      acc[(mq)*4+f][(nq)*2+g2] = __builtin_amdgcn_mfma_f32_16x16x32_bf16(     \
          av[f][1], bv[nq][g2][1], acc[(mq)*4+f][(nq)*2+g2], 0, 0, 0);        \
    }                                                                         \
  __builtin_amdgcn_s_setprio(0);                                              \
  __builtin_amdgcn_s_barrier();                                               \
} while(0)

__global__ __launch_bounds__(512, 2) void k_gemmM(GemmDesc gd, int shift){
  constexpr int K = 1024, NN = 1024, NT = K / 64, NIT = NT / 2;
  __shared__ u16 lds[65536];  // 128 KiB

  int tid = threadIdx.x;
  int w = tid >> 6, l = tid & 63;
  int wr = w >> 2, wc = w & 3;
  int lr = l & 15, cb = l >> 4;

  // bijective XCD swizzle over whole grid (nwg % 8 == 0 by construction)
  int nwg = gridDim.x, cpx = nwg >> 3;
  int swz = (blockIdx.x & 7) * cpx + (blockIdx.x >> 3);
  int mat = swz >> shift;
  int local = swz & ((1 << shift) - 1);
  int batch = local >> 4;
  int tile = local & 15;
  int bm = (tile >> 2) * 256, bn = (tile & 3) * 256;

  const u16* Ab = gd.A[mat] + (long)batch * gd.sA[mat] + (long)bm * K;
  const u16* Bb = gd.B[mat] + (long)batch * gd.sB[mat] + (long)bn * K;
  int epi = gd.epi[mat];

  int arow = (wr * 128 + lr) * 64;
  int brow = (wc * 64 + lr) * 64;
  int cko0 = ((cb) ^ (lr & 7)) * 8;
  int cko1 = ((4 + cb) ^ (lr & 7)) * 8;

  int srow8 = l >> 3;
  int schunk = (l & 7) ^ (l >> 3);

  auto stA = [&](int slot, int t, int q){
    #pragma unroll
    for (int j = 0; j < 2; j++){
      int wb = w * 2 + j;
      int gr = ((wb >> 3) * 128) + ((wb & 7) * 8) + q * 64;
      gload_lds16(Ab + (long)(gr + srow8) * K + t * 64 + schunk * 8,
                  (u16*)lds + slot * 16384 + gr * 64);
    }
  };
  auto stB = [&](int slot, int t, int q){
    #pragma unroll
    for (int j = 0; j < 2; j++){
      int wb = w * 2 + j;
      int gr = ((wb >> 2) * 64) + ((wb & 3) * 8) + q * 32;
      gload_lds16(Bb + (long)(gr + srow8) * K + t * 64 + schunk * 8,
                  (u16*)lds + 32768 + slot * 16384 + gr * 64);
    }
  };

  f32x4 acc[8][4] = {};
  s16x8 av[4][2];
  s16x8 bv[2][2][2];

  // prologue: t0 all 4 units -> slot0, t1 q0 units -> slot1
  stA(0, 0, 0); stB(0, 0, 0); stA(0, 0, 1); stB(0, 0, 1);
  stA(1, 1, 0); stB(1, 1, 0);
  VM8;  // Aq0(t0), Bq0(t0) landed
  __builtin_amdgcn_s_barrier();

  #pragma unroll 1
  for (int i = 0; i < NIT - 1; ++i){
    int t1 = 2 * i + 1, t2 = 2 * i + 2, t3 = 2 * i + 3;
    PH(0, 0, 0, 1, 1, stA(1, t1, 1), VM6);
    PH(0, 0, 1, 0, 1, stB(1, t1, 1), (void)0);
    PH(0, 1, 0, 1, 0, stA(0, t2, 0), (void)0);
    PH(0, 1, 1, 0, 0, stB(0, t2, 0), VM8);
    PH(1, 0, 0, 1, 1, stA(0, t2, 1), VM6);
    PH(1, 0, 1, 0, 1, stB(0, t2, 1), (void)0);
    PH(1, 1, 0, 1, 0, stA(1, t3, 0), (void)0);
    PH(1, 1, 1, 0, 0, stB(1, t3, 0), VM8);
  }
  // peeled last iteration
  {
    int t1 = NT - 1;
    PH(0, 0, 0, 1, 1, stA(1, t1, 1), VM6);
    PH(0, 0, 1, 0, 1, stB(1, t1, 1), (void)0);
    PH(0, 1, 0, 1, 0, (void)0, (void)0);
    PH(0, 1, 1, 0, 0, (void)0, VM4);
    PH(1, 0, 0, 1, 1, (void)0, VM0);
    PH(1, 0, 1, 0, 1, (void)0, (void)0);
    PH(1, 1, 0, 1, 0, (void)0, (void)0);
    PH(1, 1, 1, 0, 0, (void)0, (void)0);
  }

  // epilogue
  u16* Cb = gd.C[mat] + (long)batch * gd.sC[mat];
  float sc = gd.scale;
  float iz[4];
  if (epi == 2){
    const float* Zp = gd.Z[mat] + (long)batch * NN;
    #pragma unroll
    for (int j = 0; j < 4; j++) iz[j] = 1.0f / Zp[bn + wc * 64 + j * 16 + lr];
  }
  float cs[4] = {0.f, 0.f, 0.f, 0.f};
  int cb4 = cb * 4;
  #pragma unroll
  for (int ai = 0; ai < 8; ai++)
    #pragma unroll
    for (int j = 0; j < 4; j++)
      #pragma unroll
      for (int r = 0; r < 4; r++){
        float v = acc[ai][j][r];
        if (epi == 0) v = fmaxf(v, 0.f);
        else if (epi == 1){ v = __expf(v * sc); cs[j] += v; }
        else if (epi == 2) v = fmaxf(v, 0.f) * iz[j];
        int row = bm + wr * 128 + ai * 16 + cb4 + r;
        int col = bn + wc * 64 + j * 16 + lr;
        Cb[(long)row * NN + col] = f2bf(v);
      }
  if (epi == 1){
    float* Zp = gd.Z[mat] + (long)batch * NN;
    #pragma unroll
    for (int j = 0; j < 4; j++){
      float c = cs[j];
      c += __shfl_xor(c, 16);
      c += __shfl_xor(c, 32);
      if (l < 16) atomicAdd(&Zp[bn + wc * 64 + j * 16 + l], c);
    }
  }
}

// ---------------- final: out = l2n(l2n(V+w1t) + l2n(T*rT+w2t)) per column ----------------
__global__ __launch_bounds__(1024) void k_final(const float* V, const float* T_,
                                                const float* rT, const u16* w1t,
                                                const u16* w2t, float* out, int bo){
  __shared__ float red[64][16][13];
  __shared__ float fac[3][64];
  int b = blockIdx.y;
  int c0 = blockIdx.x * 64;
  long gbase = (long)(bo + b) * DIM * L + c0;
  long lbase = (long)b * DIM * L + c0;
  int cq = threadIdx.x & 15, g = threadIdx.x >> 4;
  int coff = cq * 4;
  float4 rt4 = *(const float4*)(rT + (long)b * L + c0 + coff);
  f32x4 rtv = {rt4.x, rt4.y, rt4.z, rt4.w};
  f32x4 s1 = {0.f,0.f,0.f,0.f}, s2 = {0.f,0.f,0.f,0.f}, s12 = {0.f,0.f,0.f,0.f};
  #pragma unroll 8
  for (int d = g; d < DIM; d += 64){
    long o = (long)d * L + coff;
    float4 v = *(const float4*)(V + gbase + o);
    float4 t = *(const float4*)(T_ + gbase + o);
    ushort4 w1 = *(const ushort4*)(w1t + lbase + o);
    ushort4 w2 = *(const ushort4*)(w2t + lbase + o);
    f32x4 a = {v.x + bf2f(w1.x), v.y + bf2f(w1.y), v.z + bf2f(w1.z), v.w + bf2f(w1.w)};
    f32x4 tt = {t.x, t.y, t.z, t.w};
    f32x4 bb = tt * rtv;
    bb[0] += bf2f(w2.x); bb[1] += bf2f(w2.y); bb[2] += bf2f(w2.z); bb[3] += bf2f(w2.w);
    s1 += a * a; s2 += bb * bb; s12 += a * bb;
  }
  #pragma unroll
  for (int e = 0; e < 4; e++){
    red[g][cq][e] = s1[e];
    red[g][cq][4 + e] = s2[e];
    red[g][cq][8 + e] = s12[e];
  }
  __syncthreads();
  if (threadIdx.x < 192){
    int q = threadIdx.x / 12, s = threadIdx.x % 12;
    float acc = 0.f;
    #pragma unroll 8
    for (int gg = 0; gg < 64; gg++) acc += red[gg][q][s];
    red[0][q][s] = acc;
  }
  __syncthreads();
  if (threadIdx.x < 64){
    int c = threadIdx.x;
    float n1 = red[0][c >> 2][c & 3];
    float n2 = red[0][c >> 2][4 + (c & 3)];
    float cc = red[0][c >> 2][8 + (c & 3)];
    float rn1 = 1.f / fmaxf(sqrtf(n1), 1e-12f);
    float rn2 = 1.f / fmaxf(sqrtf(n2), 1e-12f);
    float n3 = n1 * rn1 * rn1 + 2.f * cc * rn1 * rn2 + n2 * rn2 * rn2;
    float rn3 = 1.f / fmaxf(sqrtf(n3), 1e-12f);
    fac[0][c] = rn1; fac[1][c] = rn2; fac[2][c] = rn3;
  }
  __syncthreads();
  f32x4 f1, f2, f3;
  #pragma unroll
  for (int e = 0; e < 4; e++){
    f1[e] = fac[0][coff + e]; f2[e] = fac[1][coff + e]; f3[e] = fac[2][coff + e];
  }
  #pragma unroll 8
  for (int d = g; d < DIM; d += 64){
    long o = (long)d * L + coff;
    float4 v = *(const float4*)(V + gbase + o);
    float4 t = *(const float4*)(T_ + gbase + o);
    ushort4 w1 = *(const ushort4*)(w1t + lbase + o);
    ushort4 w2 = *(const ushort4*)(w2t + lbase + o);
    f32x4 a = {v.x + bf2f(w1.x), v.y + bf2f(w1.y), v.z + bf2f(w1.z), v.w + bf2f(w1.w)};
    f32x4 tt = {t.x, t.y, t.z, t.w};
    f32x4 bb = tt * rtv;
    bb[0] += bf2f(w2.x); bb[1] += bf2f(w2.y); bb[2] += bf2f(w2.z); bb[3] += bf2f(w2.w);
    f32x4 r = (a * f1 + bb * f2) * f3;
    float4 st = {r[0], r[1], r[2], r[3]};
    *(float4*)(out + gbase + o) = st;
  }
}

extern "C" void kernel_launch(void* const* d_in, const int* in_sizes, int n_in,
                              void* d_out, int out_size, void* d_ws, size_t ws_size,
                              hipStream_t stream) {
  const float* V = (const float*)d_in[0];
  const float* T = (const float*)d_in[1];
  char* ws = (char*)d_ws;
  const long MB = 1 << 20;
  float* out = (float*)d_out;

  // workspace: fixed 13MB + 7 slots x 2MB per batch = 14MB/batch
  int G = NB;
  while (G > 1 && (size_t)((13 + 14 * (long)G) * MB) > ws_size) G >>= 1;
  int shift = 4 + (31 - __builtin_clz((unsigned)G));  // log2(16G)

  u16*   Wb  = (u16*)(ws);                           // 12MB
  float* rT  = (float*)(ws + 12 * MB);               // G*L f32 (<=64KB)
  float* Z1  = (float*)(ws + 12 * MB + 128 * 1024);  // G*L f32
  float* Z2  = (float*)(ws + 12 * MB + 256 * 1024);  // G*L f32
  char*  bufs = ws + 13 * MB;
  long   BUF  = (long)G * 2 * MB;
  // 7 slots, overlaid by liveness:
  u16* S0 = (u16*)(bufs + 0 * BUF);  // Vt -> w2
  u16* S1 = (u16*)(bufs + 1 * BUF);  // Tnt
  u16* S2 = (u16*)(bufs + 2 * BUF);  // k1 -> v1
  u16* S3 = (u16*)(bufs + 3 * BUF);  // q2 -> w1
  u16* S4 = (u16*)(bufs + 4 * BUF);  // q1 -> E2
  u16* S5 = (u16*)(bufs + 5 * BUF);  // k2 -> v2
  u16* S6 = (u16*)(bufs + 6 * BUF);  // E1

  WPtrs wp;
  for (int i = 0; i < 6; i++) wp.p[i] = (const float*)d_in[2 + i];
  const u16* WQ1 = Wb + 0L * MB; const u16* WK1 = Wb + 1L * MB;
  const u16* WV1 = Wb + 2L * MB; const u16* Wq2 = Wb + 3L * MB;
  const u16* Wk2 = Wb + 4L * MB; const u16* Wv2 = Wb + 5L * MB;

  long LD = (long)L * DIM;
  const float invsq = 0.03125f;  // 1/sqrt(1024)

  u16* Vt = S0, *Tnt = S1;
  u16* k1 = S2, *q2 = S3, *q1 = S4, *k2 = S5;
  u16* E1 = S6, *E2 = S4;            // E2 over q1 (dead after D3a)
  u16* v1 = S2, *v2 = S5;            // over k1, k2 (dead after D3)
  u16* w1b = S3, *w2b = S0;          // over q2, Vt (dead after Dv)

  // D1: all 4 projections (relu)
  GemmDesc g1 = {};
  g1.A[0] = Vt;  g1.B[0] = WQ1; g1.C[0] = q1;
  g1.A[1] = Tnt; g1.B[1] = WK1; g1.C[1] = k1;
  g1.A[2] = Tnt; g1.B[2] = Wq2; g1.C[2] = q2;
  g1.A[3] = Vt;  g1.B[3] = Wk2; g1.C[3] = k2;
  for (int i = 0; i < 4; i++){ g1.sA[i] = LD; g1.sB[i] = 0; g1.sC[i] = LD;
    g1.epi[i] = 0; g1.Z[i] = Z1; }
  g1.scale = 0.f;

  // D3a: E1 = exp(q1.k1^T/32), Z1 colsum atomics
  GemmDesc g3a = {};
  for (int i = 0; i < 4; i++){ g3a.A[i] = q1; g3a.B[i] = k1; g3a.C[i] = E1;
    g3a.sA[i] = LD; g3a.sB[i] = LD; g3a.sC[i] = LD; g3a.epi[i] = 1; g3a.Z[i] = Z1; }
  g3a.scale = invsq;

  // D3b: E2 = exp(q2.k2^T/32), Z2 colsum atomics
  GemmDesc g3b = {};
  for (int i = 0; i < 4; i++){ g3b.A[i] = q2; g3b.B[i] = k2; g3b.C[i] = E2;
    g3b.sA[i] = LD; g3b.sB[i] = LD; g3b.sC[i] = LD; g3b.epi[i] = 1; g3b.Z[i] = Z2; }
  g3b.scale = invsq;

  // Dv: v1 = relu(WV1.Tnt)/Z1[col], v2 = relu(Wv2.Vt)/Z2[col]
  GemmDesc gv = {};
  gv.A[0] = WV1; gv.B[0] = Tnt; gv.C[0] = v1; gv.Z[0] = Z1;
  gv.A[1] = Wv2; gv.B[1] = Vt;  gv.C[1] = v2; gv.Z[1] = Z2;
  gv.A[2] = WV1; gv.B[2] = Tnt; gv.C[2] = v1; gv.Z[2] = Z1;
  gv.A[3] = WV1; gv.B[3] = Tnt; gv.C[3] = v1; gv.Z[3] = Z1;
  for (int i = 0; i < 4; i++){ gv.sA[i] = 0; gv.sB[i] = LD; gv.sC[i] = LD; gv.epi[i] = 2; }
  gv.scale = 0.f;

  // D4: w1 = v1.E1^T, w2 = v2.E2^T (plain)
  GemmDesc g4 = {};
  g4.A[0] = v1; g4.B[0] = E1; g4.C[0] = w1b; g4.Z[0] = Z1;
  g4.A[1] = v2; g4.B[1] = E2; g4.C[1] = w2b; g4.Z[1] = Z2;
  g4.A[2] = v1; g4.B[2] = E1; g4.C[2] = w1b; g4.Z[2] = Z1;
  g4.A[3] = v1; g4.B[3] = E1; g4.C[3] = w1b; g4.Z[3] = Z1;
  for (int i = 0; i < 4; i++){ g4.sA[i] = LD; g4.sB[i] = LD; g4.sC[i] = LD; g4.epi[i] = 3; }
  g4.scale = 0.f;

  k_wconv<<<6144, 256, 0, stream>>>(wp, Wb);

  for (int bo = 0; bo < NB; bo += G){
    k_transpose<<<dim3(256, G), 256, 0, stream>>>(V, Vt, bo);
    k_tnorm<<<dim3(16, G), 256, 0, stream>>>(T, Tnt, rT, Z1, Z2, bo);

    k_gemmM<<<4 * 16 * G, 512, 0, stream>>>(g1, shift);   // q1,k1,q2,k2
    k_gemmM<<<1 * 16 * G, 512, 0, stream>>>(g3a, shift);  // E1 + Z1
    k_gemmM<<<1 * 16 * G, 512, 0, stream>>>(g3b, shift);  // E2 + Z2
    k_gemmM<<<2 * 16 * G, 512, 0, stream>>>(gv, shift);   // v1,v2 (x 1/Z)
    k_gemmM<<<2 * 16 * G, 512, 0, stream>>>(g4, shift);   // w1,w2

    k_final<<<dim3(16, G), 1024, 0, stream>>>(V, T, rT, w1b, w2b, out, bo);
  }
}

// Round 11
// 579.680 us; speedup vs baseline: 1.0532x; 1.0532x over previous
//
#include <hip/hip_runtime.h>

#define L 1024
#define DIM 1024
#define NB 16

typedef unsigned short u16;
typedef __attribute__((ext_vector_type(4))) float f32x4;
typedef __attribute__((ext_vector_type(8))) short s16x8;

__device__ __forceinline__ float bf2f(u16 x){
  union { unsigned u; float f; } c; c.u = ((unsigned)x) << 16; return c.f;
}
__device__ __forceinline__ u16 f2bf(float f){
  union { float f; unsigned u; } c; c.f = f;
  unsigned r = c.u + 0x7fffu + ((c.u >> 16) & 1u);
  return (u16)(r >> 16);
}
__device__ __forceinline__ void gload_lds16(const void* g, void* l){
  __builtin_amdgcn_global_load_lds(
      (const __attribute__((address_space(1))) void*)g,
      (__attribute__((address_space(3))) void*)l, 16, 0, 0);
}

// ---------------- weights fp32 -> bf16 (once) ----------------
struct WPtrs { const float* p[6]; };

__global__ __launch_bounds__(256) void k_wconv(WPtrs wp, u16* out){
  long idx = (long)blockIdx.x * blockDim.x + threadIdx.x;
  long base = idx * 4;
  int w = (int)(base >> 20);
  long off = base & ((1 << 20) - 1);
  float4 v = *(const float4*)(wp.p[w] + off);
  ushort4 o;
  o.x = f2bf(v.x); o.y = f2bf(v.y); o.z = f2bf(v.z); o.w = f2bf(v.w);
  *(ushort4*)(out + base) = o;
}

// ---------------- V [D,L] f32 -> Vt [L,D] bf16 (vectorized) ----------------
__global__ __launch_bounds__(256) void k_transpose(const float* X, u16* Xt, int bo){
  __shared__ u16 tile[64][68];
  int b = blockIdx.y;
  int d0 = (blockIdx.x >> 4) * 64;
  int l0 = (blockIdx.x & 15) * 64;
  const float* Xb = X + (long)(bo + b) * DIM * L;
  u16* Xtb = Xt + (long)b * L * DIM;
  int q = threadIdx.x & 15, g = threadIdx.x >> 4;
  for (int r = g; r < 64; r += 16){
    float4 v = *(const float4*)(Xb + (long)(d0 + r) * L + l0 + q * 4);
    ushort4 h; h.x = f2bf(v.x); h.y = f2bf(v.y); h.z = f2bf(v.z); h.w = f2bf(v.w);
    *(ushort4*)&tile[r][q * 4] = h;
  }
  __syncthreads();
  for (int r = g; r < 64; r += 16){
    ushort4 h;
    h.x = tile[q * 4 + 0][r]; h.y = tile[q * 4 + 1][r];
    h.z = tile[q * 4 + 2][r]; h.w = tile[q * 4 + 3][r];
    *(ushort4*)&Xtb[(long)(l0 + r) * DIM + d0 + q * 4] = h;
  }
}

// ------- T: column inv-norm rT + normalized transpose Tnt; also zeros Z1,Z2 -------
__global__ __launch_bounds__(256) void k_tnorm(const float* T_, u16* Tnt, float* rT,
                                               float* Z1, float* Z2, int bo){
  __shared__ float red[16][16][5];
  __shared__ float rn[64];
  __shared__ u16 tile[64][68];
  int b = blockIdx.y; int l0 = blockIdx.x * 64;
  const float* Tb = T_ + (long)(bo + b) * DIM * L;
  int q = threadIdx.x & 15, g = threadIdx.x >> 4;
  if (threadIdx.x < 64){
    Z1[(long)b * L + l0 + threadIdx.x] = 0.f;
    Z2[(long)b * L + l0 + threadIdx.x] = 0.f;
  }
  f32x4 ss = {0.f, 0.f, 0.f, 0.f};
  for (int d = g; d < DIM; d += 16){
    float4 v = *(const float4*)(Tb + (long)d * L + l0 + q * 4);
    f32x4 vv = {v.x, v.y, v.z, v.w};
    ss += vv * vv;
  }
  #pragma unroll
  for (int e = 0; e < 4; e++) red[g][q][e] = ss[e];
  __syncthreads();
  if (threadIdx.x < 64){
    int c = threadIdx.x;
    float n = 0.f;
    #pragma unroll
    for (int gg = 0; gg < 16; gg++) n += red[gg][c >> 2][c & 3];
    float r = 1.0f / fmaxf(sqrtf(n), 1e-12f);
    rn[c] = r;
    rT[(long)b * L + l0 + c] = r;
  }
  __syncthreads();
  float r0 = rn[q * 4], r1 = rn[q * 4 + 1], r2 = rn[q * 4 + 2], r3 = rn[q * 4 + 3];
  u16* Tntb = Tnt + (long)b * L * DIM;
  for (int ch = 0; ch < 16; ch++){
    int dbase = ch * 64;
    for (int r = g; r < 64; r += 16){
      float4 v = *(const float4*)(Tb + (long)(dbase + r) * L + l0 + q * 4);
      ushort4 h;
      h.x = f2bf(v.x * r0); h.y = f2bf(v.y * r1);
      h.z = f2bf(v.z * r2); h.w = f2bf(v.w * r3);
      *(ushort4*)&tile[r][q * 4] = h;
    }
    __syncthreads();
    for (int r = g; r < 64; r += 16){
      ushort4 h;
      h.x = tile[q * 4 + 0][r]; h.y = tile[q * 4 + 1][r];
      h.z = tile[q * 4 + 2][r]; h.w = tile[q * 4 + 3][r];
      *(ushort4*)&Tntb[(long)(l0 + r) * DIM + dbase + q * 4] = h;
    }
    __syncthreads();
  }
}

// ================= merged 256x256 8-phase bt-GEMM =================
// Up to 4 independent sub-GEMMs per dispatch. Template-form phases
// (lgkmcnt(0) after barrier), counted vmcnt ledger (min lead 3 phases).
// epi: 0 relu | 1 exp(acc*scale) + column-sum atomics to Z | 2 relu * (1/Z[col]) | 3 plain

struct GemmDesc {
  const u16* A[4]; const u16* B[4]; u16* C[4];
  float* Z[4];
  long sA[4], sB[4], sC[4];
  int epi[4];
  float scale;
};

#define VM6 asm volatile("s_waitcnt vmcnt(6)" ::: "memory")
#define VM8 asm volatile("s_waitcnt vmcnt(8)" ::: "memory")
#define VM4 asm volatile("s_waitcnt vmcnt(4)" ::: "memory")
#define VM0 asm volatile("s_waitcnt vmcnt(0)" ::: "memory")

#define PH(slot, mq, nq, LA, LB, STAGE, WAITC) do {                           \
  if (LA){                                                                    \
    _Pragma("unroll")                                                         \
    for (int f = 0; f < 4; f++){                                              \
      av[f][0] = *(const s16x8*)&lds[(slot)*16384 + arow + (mq)*4096 + f*1024 + cko0]; \
      av[f][1] = *(const s16x8*)&lds[(slot)*16384 + arow + (mq)*4096 + f*1024 + cko1]; \
    }                                                                         \
  }                                                                           \
  if (LB){                                                                    \
    _Pragma("unroll")                                                         \
    for (int g2 = 0; g2 < 2; g2++){                                           \
      bv[nq][g2][0] = *(const s16x8*)&lds[32768 + (slot)*16384 + brow + (nq)*2048 + g2*1024 + cko0]; \
      bv[nq][g2][1] = *(const s16x8*)&lds[32768 + (slot)*16384 + brow + (nq)*2048 + g2*1024 + cko1]; \
    }                                                                         \
  }                                                                           \
  STAGE;                                                                      \
  WAITC;                                                                      \
  __builtin_amdgcn_s_barrier();                                               \
  asm volatile("s_waitcnt lgkmcnt(0)" ::: "memory");                          \
  __builtin_amdgcn_s_setprio(1);                                              \
  _Pragma("unroll")                                                           \
  for (int f = 0; f < 4; f++)                                                 \
    _Pragma("unroll")                                                         \
    for (int g2 = 0; g2 < 2; g2++){                                           \
      acc[(mq)*4+f][(nq)*2+g2] = __builtin_amdgcn_mfma_f32_16x16x32_bf16(     \
          av[f][0], bv[nq][g2][0], acc[(mq)*4+f][(nq)*2+g2], 0, 0, 0);        \
      acc[(mq)*4+f][(nq)*2+g2] = __builtin_amdgcn_mfma_f32_16x16x32_bf16(     \
          av[f][1], bv[nq][g2][1], acc[(mq)*4+f][(nq)*2+g2], 0, 0, 0);        \
    }                                                                         \
  __builtin_amdgcn_s_setprio(0);                                              \
  __builtin_amdgcn_s_barrier();                                               \
} while(0)

__global__ __launch_bounds__(512, 2) void k_gemmM(GemmDesc gd, int shift){
  constexpr int K = 1024, NN = 1024, NT = K / 64, NIT = NT / 2;
  __shared__ u16 lds[65536];  // 128 KiB

  int tid = threadIdx.x;
  int w = tid >> 6, l = tid & 63;
  int wr = w >> 2, wc = w & 3;
  int lr = l & 15, cb = l >> 4;

  // bijective XCD swizzle over whole grid (nwg % 8 == 0 by construction)
  int nwg = gridDim.x, cpx = nwg >> 3;
  int swz = (blockIdx.x & 7) * cpx + (blockIdx.x >> 3);
  int mat = swz >> shift;
  int local = swz & ((1 << shift) - 1);
  int batch = local >> 4;
  int tile = local & 15;
  int bm = (tile >> 2) * 256, bn = (tile & 3) * 256;

  const u16* Ab = gd.A[mat] + (long)batch * gd.sA[mat] + (long)bm * K;
  const u16* Bb = gd.B[mat] + (long)batch * gd.sB[mat] + (long)bn * K;
  int epi = gd.epi[mat];

  int arow = (wr * 128 + lr) * 64;
  int brow = (wc * 64 + lr) * 64;
  int cko0 = ((cb) ^ (lr & 7)) * 8;
  int cko1 = ((4 + cb) ^ (lr & 7)) * 8;

  int srow8 = l >> 3;
  int schunk = (l & 7) ^ (l >> 3);

  auto stA = [&](int slot, int t, int q){
    #pragma unroll
    for (int j = 0; j < 2; j++){
      int wb = w * 2 + j;
      int gr = ((wb >> 3) * 128) + ((wb & 7) * 8) + q * 64;
      gload_lds16(Ab + (long)(gr + srow8) * K + t * 64 + schunk * 8,
                  (u16*)lds + slot * 16384 + gr * 64);
    }
  };
  auto stB = [&](int slot, int t, int q){
    #pragma unroll
    for (int j = 0; j < 2; j++){
      int wb = w * 2 + j;
      int gr = ((wb >> 2) * 64) + ((wb & 3) * 8) + q * 32;
      gload_lds16(Bb + (long)(gr + srow8) * K + t * 64 + schunk * 8,
                  (u16*)lds + 32768 + slot * 16384 + gr * 64);
    }
  };

  f32x4 acc[8][4] = {};
  s16x8 av[4][2];
  s16x8 bv[2][2][2];

  // prologue: t0 all 4 units -> slot0, t1 q0 units -> slot1
  stA(0, 0, 0); stB(0, 0, 0); stA(0, 0, 1); stB(0, 0, 1);
  stA(1, 1, 0); stB(1, 1, 0);
  VM8;  // Aq0(t0), Bq0(t0) landed
  __builtin_amdgcn_s_barrier();

  #pragma unroll 1
  for (int i = 0; i < NIT - 1; ++i){
    int t1 = 2 * i + 1, t2 = 2 * i + 2, t3 = 2 * i + 3;
    PH(0, 0, 0, 1, 1, stA(1, t1, 1), VM6);
    PH(0, 0, 1, 0, 1, stB(1, t1, 1), (void)0);
    PH(0, 1, 0, 1, 0, stA(0, t2, 0), (void)0);
    PH(0, 1, 1, 0, 0, stB(0, t2, 0), VM8);
    PH(1, 0, 0, 1, 1, stA(0, t2, 1), VM6);
    PH(1, 0, 1, 0, 1, stB(0, t2, 1), (void)0);
    PH(1, 1, 0, 1, 0, stA(1, t3, 0), (void)0);
    PH(1, 1, 1, 0, 0, stB(1, t3, 0), VM8);
  }
  // peeled last iteration
  {
    int t1 = NT - 1;
    PH(0, 0, 0, 1, 1, stA(1, t1, 1), VM6);
    PH(0, 0, 1, 0, 1, stB(1, t1, 1), (void)0);
    PH(0, 1, 0, 1, 0, (void)0, (void)0);
    PH(0, 1, 1, 0, 0, (void)0, VM4);
    PH(1, 0, 0, 1, 1, (void)0, VM0);
    PH(1, 0, 1, 0, 1, (void)0, (void)0);
    PH(1, 1, 0, 1, 0, (void)0, (void)0);
    PH(1, 1, 1, 0, 0, (void)0, (void)0);
  }

  // epilogue
  u16* Cb = gd.C[mat] + (long)batch * gd.sC[mat];
  float sc = gd.scale;
  float iz[4];
  if (epi == 2){
    const float* Zp = gd.Z[mat] + (long)batch * NN;
    #pragma unroll
    for (int j = 0; j < 4; j++) iz[j] = 1.0f / Zp[bn + wc * 64 + j * 16 + lr];
  }
  float cs[4] = {0.f, 0.f, 0.f, 0.f};
  int cb4 = cb * 4;
  #pragma unroll
  for (int ai = 0; ai < 8; ai++)
    #pragma unroll
    for (int j = 0; j < 4; j++)
      #pragma unroll
      for (int r = 0; r < 4; r++){
        float v = acc[ai][j][r];
        if (epi == 0) v = fmaxf(v, 0.f);
        else if (epi == 1){ v = __expf(v * sc); cs[j] += v; }
        else if (epi == 2) v = fmaxf(v, 0.f) * iz[j];
        int row = bm + wr * 128 + ai * 16 + cb4 + r;
        int col = bn + wc * 64 + j * 16 + lr;
        Cb[(long)row * NN + col] = f2bf(v);
      }
  if (epi == 1){
    float* Zp = gd.Z[mat] + (long)batch * NN;
    #pragma unroll
    for (int j = 0; j < 4; j++){
      float c = cs[j];
      c += __shfl_xor(c, 16);
      c += __shfl_xor(c, 32);
      if (l < 16) atomicAdd(&Zp[bn + wc * 64 + j * 16 + l], c);
    }
  }
}

// ---------------- final: out = l2n(l2n(V+w1t) + l2n(T*rT+w2t)) per column ----------------
__global__ __launch_bounds__(1024) void k_final(const float* V, const float* T_,
                                                const float* rT, const u16* w1t,
                                                const u16* w2t, float* out, int bo){
  __shared__ float red[64][16][13];
  __shared__ float fac[3][64];
  int b = blockIdx.y;
  int c0 = blockIdx.x * 64;
  long gbase = (long)(bo + b) * DIM * L + c0;
  long lbase = (long)b * DIM * L + c0;
  int cq = threadIdx.x & 15, g = threadIdx.x >> 4;
  int coff = cq * 4;
  float4 rt4 = *(const float4*)(rT + (long)b * L + c0 + coff);
  f32x4 rtv = {rt4.x, rt4.y, rt4.z, rt4.w};
  f32x4 s1 = {0.f,0.f,0.f,0.f}, s2 = {0.f,0.f,0.f,0.f}, s12 = {0.f,0.f,0.f,0.f};
  #pragma unroll 4
  for (int d = g; d < DIM; d += 64){
    long o = (long)d * L + coff;
    float4 v = *(const float4*)(V + gbase + o);
    float4 t = *(const float4*)(T_ + gbase + o);
    ushort4 w1 = *(const ushort4*)(w1t + lbase + o);
    ushort4 w2 = *(const ushort4*)(w2t + lbase + o);
    f32x4 a = {v.x + bf2f(w1.x), v.y + bf2f(w1.y), v.z + bf2f(w1.z), v.w + bf2f(w1.w)};
    f32x4 tt = {t.x, t.y, t.z, t.w};
    f32x4 bb = tt * rtv;
    bb[0] += bf2f(w2.x); bb[1] += bf2f(w2.y); bb[2] += bf2f(w2.z); bb[3] += bf2f(w2.w);
    s1 += a * a; s2 += bb * bb; s12 += a * bb;
  }
  #pragma unroll
  for (int e = 0; e < 4; e++){
    red[g][cq][e] = s1[e];
    red[g][cq][4 + e] = s2[e];
    red[g][cq][8 + e] = s12[e];
  }
  __syncthreads();
  if (threadIdx.x < 192){
    int q = threadIdx.x / 12, s = threadIdx.x % 12;
    float acc = 0.f;
    #pragma unroll 8
    for (int gg = 0; gg < 64; gg++) acc += red[gg][q][s];
    red[0][q][s] = acc;
  }
  __syncthreads();
  if (threadIdx.x < 64){
    int c = threadIdx.x;
    float n1 = red[0][c >> 2][c & 3];
    float n2 = red[0][c >> 2][4 + (c & 3)];
    float cc = red[0][c >> 2][8 + (c & 3)];
    float rn1 = 1.f / fmaxf(sqrtf(n1), 1e-12f);
    float rn2 = 1.f / fmaxf(sqrtf(n2), 1e-12f);
    float n3 = n1 * rn1 * rn1 + 2.f * cc * rn1 * rn2 + n2 * rn2 * rn2;
    float rn3 = 1.f / fmaxf(sqrtf(n3), 1e-12f);
    fac[0][c] = rn1; fac[1][c] = rn2; fac[2][c] = rn3;
  }
  __syncthreads();
  f32x4 f1, f2, f3;
  #pragma unroll
  for (int e = 0; e < 4; e++){
    f1[e] = fac[0][coff + e]; f2[e] = fac[1][coff + e]; f3[e] = fac[2][coff + e];
  }
  #pragma unroll 4
  for (int d = g; d < DIM; d += 64){
    long o = (long)d * L + coff;
    float4 v = *(const float4*)(V + gbase + o);
    float4 t = *(const float4*)(T_ + gbase + o);
    ushort4 w1 = *(const ushort4*)(w1t + lbase + o);
    ushort4 w2 = *(const ushort4*)(w2t + lbase + o);
    f32x4 a = {v.x + bf2f(w1.x), v.y + bf2f(w1.y), v.z + bf2f(w1.z), v.w + bf2f(w1.w)};
    f32x4 tt = {t.x, t.y, t.z, t.w};
    f32x4 bb = tt * rtv;
    bb[0] += bf2f(w2.x); bb[1] += bf2f(w2.y); bb[2] += bf2f(w2.z); bb[3] += bf2f(w2.w);
    f32x4 r = (a * f1 + bb * f2) * f3;
    float4 st = {r[0], r[1], r[2], r[3]};
    *(float4*)(out + gbase + o) = st;
  }
}

extern "C" void kernel_launch(void* const* d_in, const int* in_sizes, int n_in,
                              void* d_out, int out_size, void* d_ws, size_t ws_size,
                              hipStream_t stream) {
  const float* V = (const float*)d_in[0];
  const float* T = (const float*)d_in[1];
  char* ws = (char*)d_ws;
  const long MB = 1 << 20;
  float* out = (float*)d_out;

  // workspace: fixed 13MB + 7 slots x 2MB per batch = 14MB/batch
  int G = NB;
  while (G > 1 && (size_t)((13 + 14 * (long)G) * MB) > ws_size) G >>= 1;
  int shift = 4 + (31 - __builtin_clz((unsigned)G));  // log2(16G)

  u16*   Wb  = (u16*)(ws);                           // 12MB
  float* rT  = (float*)(ws + 12 * MB);               // G*L f32 (<=64KB)
  float* Z1  = (float*)(ws + 12 * MB + 128 * 1024);  // G*L f32
  float* Z2  = (float*)(ws + 12 * MB + 256 * 1024);  // G*L f32
  char*  bufs = ws + 13 * MB;
  long   BUF  = (long)G * 2 * MB;
  // 7 slots, overlaid by liveness:
  u16* S0 = (u16*)(bufs + 0 * BUF);  // Vt -> w2
  u16* S1 = (u16*)(bufs + 1 * BUF);  // Tnt
  u16* S2 = (u16*)(bufs + 2 * BUF);  // k1 -> v1
  u16* S3 = (u16*)(bufs + 3 * BUF);  // q2 -> w1
  u16* S4 = (u16*)(bufs + 4 * BUF);  // q1 -> E2
  u16* S5 = (u16*)(bufs + 5 * BUF);  // k2 -> v2
  u16* S6 = (u16*)(bufs + 6 * BUF);  // E1

  WPtrs wp;
  for (int i = 0; i < 6; i++) wp.p[i] = (const float*)d_in[2 + i];
  const u16* WQ1 = Wb + 0L * MB; const u16* WK1 = Wb + 1L * MB;
  const u16* WV1 = Wb + 2L * MB; const u16* Wq2 = Wb + 3L * MB;
  const u16* Wk2 = Wb + 4L * MB; const u16* Wv2 = Wb + 5L * MB;

  long LD = (long)L * DIM;
  const float invsq = 0.03125f;  // 1/sqrt(1024)

  u16* Vt = S0, *Tnt = S1;
  u16* k1 = S2, *q2 = S3, *q1 = S4, *k2 = S5;
  u16* E1 = S6, *E2 = S4;            // E2 over q1 (q1 dead after DE)
  u16* v1 = S2, *v2 = S5;            // over k1, k2 (dead after DE)
  u16* w1b = S3, *w2b = S0;          // over q2, Vt (dead after Dv)

  // D1: all 4 projections (relu)
  GemmDesc g1 = {};
  g1.A[0] = Vt;  g1.B[0] = WQ1; g1.C[0] = q1;
  g1.A[1] = Tnt; g1.B[1] = WK1; g1.C[1] = k1;
  g1.A[2] = Tnt; g1.B[2] = Wq2; g1.C[2] = q2;
  g1.A[3] = Vt;  g1.B[3] = Wk2; g1.C[3] = k2;
  for (int i = 0; i < 4; i++){ g1.sA[i] = LD; g1.sB[i] = 0; g1.sC[i] = LD;
    g1.epi[i] = 0; g1.Z[i] = Z1; }
  g1.scale = 0.f;

  // DE: E1 = exp(q1.k1^T/32) + Z1, E2 = exp(q2.k2^T/32) + Z2  (merged)
  GemmDesc ge = {};
  ge.A[0] = q1; ge.B[0] = k1; ge.C[0] = E1; ge.Z[0] = Z1;
  ge.A[1] = q2; ge.B[1] = k2; ge.C[1] = E2; ge.Z[1] = Z2;
  ge.A[2] = q1; ge.B[2] = k1; ge.C[2] = E1; ge.Z[2] = Z1;
  ge.A[3] = q1; ge.B[3] = k1; ge.C[3] = E1; ge.Z[3] = Z1;
  for (int i = 0; i < 4; i++){ ge.sA[i] = LD; ge.sB[i] = LD; ge.sC[i] = LD; ge.epi[i] = 1; }
  ge.scale = invsq;

  // Dv: v1 = relu(WV1.Tnt)/Z1[col], v2 = relu(Wv2.Vt)/Z2[col]
  GemmDesc gv = {};
  gv.A[0] = WV1; gv.B[0] = Tnt; gv.C[0] = v1; gv.Z[0] = Z1;
  gv.A[1] = Wv2; gv.B[1] = Vt;  gv.C[1] = v2; gv.Z[1] = Z2;
  gv.A[2] = WV1; gv.B[2] = Tnt; gv.C[2] = v1; gv.Z[2] = Z1;
  gv.A[3] = WV1; gv.B[3] = Tnt; gv.C[3] = v1; gv.Z[3] = Z1;
  for (int i = 0; i < 4; i++){ gv.sA[i] = 0; gv.sB[i] = LD; gv.sC[i] = LD; gv.epi[i] = 2; }
  gv.scale = 0.f;

  // D4: w1 = v1.E1^T, w2 = v2.E2^T (plain)
  GemmDesc g4 = {};
  g4.A[0] = v1; g4.B[0] = E1; g4.C[0] = w1b; g4.Z[0] = Z1;
  g4.A[1] = v2; g4.B[1] = E2; g4.C[1] = w2b; g4.Z[1] = Z2;
  g4.A[2] = v1; g4.B[2] = E1; g4.C[2] = w1b; g4.Z[2] = Z1;
  g4.A[3] = v1; g4.B[3] = E1; g4.C[3] = w1b; g4.Z[3] = Z1;
  for (int i = 0; i < 4; i++){ g4.sA[i] = LD; g4.sB[i] = LD; g4.sC[i] = LD; g4.epi[i] = 3; }
  g4.scale = 0.f;

  k_wconv<<<6144, 256, 0, stream>>>(wp, Wb);

  for (int bo = 0; bo < NB; bo += G){
    k_transpose<<<dim3(256, G), 256, 0, stream>>>(V, Vt, bo);
    k_tnorm<<<dim3(16, G), 256, 0, stream>>>(T, Tnt, rT, Z1, Z2, bo);

    k_gemmM<<<4 * 16 * G, 512, 0, stream>>>(g1, shift);   // q1,k1,q2,k2
    k_gemmM<<<2 * 16 * G, 512, 0, stream>>>(ge, shift);   // E1+Z1, E2+Z2
    k_gemmM<<<2 * 16 * G, 512, 0, stream>>>(gv, shift);   // v1,v2 (x 1/Z)
    k_gemmM<<<2 * 16 * G, 512, 0, stream>>>(g4, shift);   // w1,w2

    k_final<<<dim3(16, G), 1024, 0, stream>>>(V, T, rT, w1b, w2b, out, bo);
  }
}